// Round 1
// baseline (7236.884 us; speedup 1.0000x reference)
//
#include <hip/hip_runtime.h>
#include <hip/hip_bf16.h>

// Cuboid self-attention: B=4, T=16, H=56, W=56, C=256, NH=8, hd=32
// cuboid (2,7,7) -> nc=512 cuboids of vol=98; shift (1,3,3)
#define T_   16
#define H_   56
#define W_   56
#define C_   256
#define NH_  8
#define HD_  32
#define NC_  512
#define VOL_ 98

__device__ __forceinline__ float bflo(unsigned u) { return __uint_as_float(u << 16); }
__device__ __forceinline__ float bfhi(unsigned u) { return __uint_as_float(u & 0xffff0000u); }
__device__ __forceinline__ unsigned short f2bf(float f) {
    unsigned u = __float_as_uint(f);
    unsigned r = (u + 0x7fffu + ((u >> 16) & 1u)) >> 16;
    return (unsigned short)r;
}
__device__ __forceinline__ float bf2f(unsigned short us) {
    return __uint_as_float(((unsigned)us) << 16);
}

// ---------------------------------------------------------------------------
// Kernel 1: LN + shift + reorder + QKV + masked attention -> ao (bf16 in ws)
// one block per (b, cuboid); 256 threads = 4 waves
// ---------------------------------------------------------------------------
__global__ __launch_bounds__(256, 2)
void k_ln_qkv_attn(const float* __restrict__ x, const float* __restrict__ gamma,
                   const float* __restrict__ beta, const float* __restrict__ wqkv,
                   unsigned short* __restrict__ ao)
{
    __shared__ __align__(16) unsigned short rn[VOL_][C_];   // 50176 B, normalized tile
    __shared__ __align__(16) unsigned short kT[HD_][100];   // 6400 B, K transposed (pad 100)
    __shared__ __align__(16) unsigned short vb[VOL_][34];   // 6664 B, V (pad 34)
    __shared__ float pbuf[4][VOL_];                         // 1568 B, per-wave p row
    __shared__ unsigned char labs[VOL_];                    // mask labels

    const int bid = blockIdx.x;
    const int b  = bid >> 9, n = bid & 511;
    const int ti = n >> 6, hi = (n >> 3) & 7, wi = n & 7;
    const int tid = threadIdx.x;
    const int lane = tid & 63, wv = tid >> 6;

    // ---- LayerNorm + roll(-1,-3,-3) gather, write bf16 tile ----
    const float4 g  = *(const float4*)(gamma + lane*4);
    const float4 be = *(const float4*)(beta  + lane*4);
    for (int i = wv; i < VOL_; i += 4) {
        int vt = (i >= 49) ? 1 : 0;
        int r  = i - vt*49;
        int vh = r / 7, vw = r - vh*7;
        int t = ti*2 + vt, h = hi*7 + vh, w = wi*7 + vw;
        int ts = (t + 1) & 15;
        int hs = h + 3; if (hs >= 56) hs -= 56;
        int ws2 = w + 3; if (ws2 >= 56) ws2 -= 56;
        const float* xp = x + ((((size_t)b*16 + ts)*56 + hs)*56 + ws2)*256 + lane*4;
        float4 xv = *(const float4*)xp;
        float s  = xv.x + xv.y + xv.z + xv.w;
        float s2 = xv.x*xv.x + xv.y*xv.y + xv.z*xv.z + xv.w*xv.w;
        #pragma unroll
        for (int o = 1; o < 64; o <<= 1) { s += __shfl_xor(s, o); s2 += __shfl_xor(s2, o); }
        float mu  = s  * (1.0f/256.0f);
        float var = s2 * (1.0f/256.0f) - mu*mu;
        float rs  = rsqrtf(var + 1e-5f);
        int c = lane*4;
        rn[i][c+0] = f2bf((xv.x - mu)*rs*g.x + be.x);
        rn[i][c+1] = f2bf((xv.y - mu)*rs*g.y + be.y);
        rn[i][c+2] = f2bf((xv.z - mu)*rs*g.z + be.z);
        rn[i][c+3] = f2bf((xv.w - mu)*rs*g.w + be.w);
    }
    if (tid < VOL_) {
        int i = tid;
        int vt = (i >= 49) ? 1 : 0;
        int r  = i - vt*49;
        int vh = r / 7, vw = r - vh*7;
        int t = ti*2 + vt, h = hi*7 + vh, w = wi*7 + vw;
        int tr = (t < 14) ? 0 : ((t < 15) ? 1 : 2);
        int hr = (h < 49) ? 0 : ((h < 53) ? 1 : 2);
        int wr = (w < 49) ? 0 : ((w < 53) ? 1 : 2);
        labs[i] = (unsigned char)(tr*9 + hr*3 + wr);
    }
    __syncthreads();

    for (int hh = 0; hh < NH_; ++hh) {
        // ---- K,V projection for this head into LDS ----
        {
            const int j = tid & 31, r8 = tid >> 5;
            const float* wk  = wqkv + (size_t)(256 + hh*32 + j)*256;
            const float* wvr = wqkv + (size_t)(512 + hh*32 + j)*256;
            float ack[13], acv[13];
            #pragma unroll
            for (int kk = 0; kk < 13; ++kk) { ack[kk] = 0.f; acv[kk] = 0.f; }
            for (int c0 = 0; c0 < 256; c0 += 8) {
                float4 a0 = *(const float4*)(wk  + c0);
                float4 a1 = *(const float4*)(wk  + c0 + 4);
                float4 b0 = *(const float4*)(wvr + c0);
                float4 b1 = *(const float4*)(wvr + c0 + 4);
                #pragma unroll
                for (int kk = 0; kk < 13; ++kk) {
                    int v = r8 + 8*kk;
                    if (v < VOL_) {
                        uint4 u = *(const uint4*)(&rn[v][c0]);
                        float f0 = bflo(u.x), f1 = bfhi(u.x);
                        float f2 = bflo(u.y), f3 = bfhi(u.y);
                        float f4 = bflo(u.z), f5 = bfhi(u.z);
                        float f6 = bflo(u.w), f7 = bfhi(u.w);
                        ack[kk] += f0*a0.x + f1*a0.y + f2*a0.z + f3*a0.w
                                 + f4*a1.x + f5*a1.y + f6*a1.z + f7*a1.w;
                        acv[kk] += f0*b0.x + f1*b0.y + f2*b0.z + f3*b0.w
                                 + f4*b1.x + f5*b1.y + f6*b1.z + f7*b1.w;
                    }
                }
            }
            #pragma unroll
            for (int kk = 0; kk < 13; ++kk) {
                int v = r8 + 8*kk;
                if (v < VOL_) {
                    kT[j][v] = f2bf(ack[kk]);
                    vb[v][j] = f2bf(acv[kk]);
                }
            }
        }
        __syncthreads();

        // ---- attention rows (wave wv handles rows wv, wv+4, ...) ----
        for (int i = wv; i < VOL_; i += 4) {
            const int lab_i = labs[i];
            // q[i][j], j = lane&31, c-half = lane>>5
            const int j = lane & 31, half = lane >> 5;
            const float* wq = wqkv + (size_t)(hh*32 + j)*256 + half*128;
            const unsigned short* rrow = &rn[i][half*128];
            float acc = 0.f;
            for (int c0 = 0; c0 < 128; c0 += 8) {
                float4 a0 = *(const float4*)(wq + c0);
                float4 a1 = *(const float4*)(wq + c0 + 4);
                uint4 u = *(const uint4*)(rrow + c0);
                acc += bflo(u.x)*a0.x + bfhi(u.x)*a0.y + bflo(u.y)*a0.z + bfhi(u.y)*a0.w
                     + bflo(u.z)*a1.x + bfhi(u.z)*a1.y + bflo(u.w)*a1.z + bfhi(u.w)*a1.w;
            }
            acc += __shfl_down(acc, 32);
            float qv = acc * 0.17677669529663687f;   // * hd^-0.5, valid on lanes 0..31

            // scores for columns j1=lane, j2=lane+64
            const int j1 = lane;
            const int j2 = lane + 64;
            const bool has2 = (j2 < VOL_);
            const int j2c = has2 ? j2 : (VOL_ - 1);
            float s1 = 0.f, s2 = 0.f;
            #pragma unroll
            for (int d = 0; d < 32; ++d) {
                float qd = __shfl(qv, d);
                s1 += qd * bf2f(kT[d][j1]);
                s2 += qd * bf2f(kT[d][j2c]);
            }
            const bool m1 = (labs[j1] == lab_i);
            const bool m2 = has2 && (labs[j2c] == lab_i);
            float mx = fmaxf(m1 ? s1 : -1e30f, m2 ? s2 : -1e30f);
            #pragma unroll
            for (int o = 1; o < 64; o <<= 1) mx = fmaxf(mx, __shfl_xor(mx, o));
            float e1 = m1 ? __expf(s1 - mx) : 0.f;
            float e2 = m2 ? __expf(s2 - mx) : 0.f;
            float sm = e1 + e2;
            #pragma unroll
            for (int o = 1; o < 64; o <<= 1) sm += __shfl_xor(sm, o);
            float inv = 1.0f / sm;
            pbuf[wv][j1] = e1 * inv;
            if (has2) pbuf[wv][j2] = e2 * inv;
            // ensure this wave's pbuf writes are complete before cross-lane reads
            asm volatile("s_waitcnt lgkmcnt(0)" ::: "memory");

            // PV: lanes 0..31 sum j in [0,49), lanes 32..63 sum j in [49,98)
            const int d = lane & 31;
            const int jb = half * 49;
            float ov = 0.f;
            #pragma unroll 7
            for (int jj = 0; jj < 49; ++jj) {
                ov += pbuf[wv][jb + jj] * bf2f(vb[jb + jj][d]);
            }
            ov += __shfl_down(ov, 32);
            if (lane < 32) {
                ao[((size_t)(b*512 + n)*VOL_ + i)*C_ + hh*32 + d] = f2bf(ov);
            }
        }
        __syncthreads();
    }
}

// ---------------------------------------------------------------------------
// Kernel 2: output projection + reverse reorder + roll(+1,+3,+3) scatter
// one block per (b, cuboid); thread = output channel
// ---------------------------------------------------------------------------
__global__ __launch_bounds__(256)
void k_proj(const unsigned short* __restrict__ ao, const float* __restrict__ wp,
            const float* __restrict__ bp, float* __restrict__ y)
{
    __shared__ __align__(16) unsigned short tile[VOL_][C_];   // 50176 B
    const int bid = blockIdx.x;
    const int b  = bid >> 9, n = bid & 511;
    const int ti = n >> 6, hi = (n >> 3) & 7, wi = n & 7;
    const int tid = threadIdx.x;

    const uint4* src = (const uint4*)(ao + (size_t)bid * (VOL_*C_));
    uint4* dst = (uint4*)&tile[0][0];
    for (int idx = tid; idx < (VOL_*C_)/8; idx += 256) dst[idx] = src[idx];
    __syncthreads();

    const int dch = tid;
    const float* wrow = wp + (size_t)dch * 256;
    const float bpd = bp[dch];

    for (int v0 = 0; v0 < VOL_; v0 += 14) {
        float acc[14];
        #pragma unroll
        for (int vv = 0; vv < 14; ++vv) acc[vv] = 0.f;
        for (int c0 = 0; c0 < 256; c0 += 8) {
            float4 a0 = *(const float4*)(wrow + c0);
            float4 a1 = *(const float4*)(wrow + c0 + 4);
            #pragma unroll
            for (int vv = 0; vv < 14; ++vv) {
                uint4 u = *(const uint4*)(&tile[v0 + vv][c0]);
                acc[vv] += bflo(u.x)*a0.x + bfhi(u.x)*a0.y + bflo(u.y)*a0.z + bfhi(u.y)*a0.w
                         + bflo(u.z)*a1.x + bfhi(u.z)*a1.y + bflo(u.w)*a1.z + bfhi(u.w)*a1.w;
            }
        }
        #pragma unroll
        for (int vv = 0; vv < 14; ++vv) {
            int i = v0 + vv;
            int vt = (i >= 49) ? 1 : 0;
            int r  = i - vt*49;
            int vh = r / 7, vw = r - vh*7;
            int t = ti*2 + vt, h = hi*7 + vh, w = wi*7 + vw;
            int ts = (t + 1) & 15;
            int hs = h + 3; if (hs >= 56) hs -= 56;
            int ws2 = w + 3; if (ws2 >= 56) ws2 -= 56;
            y[((((size_t)b*16 + ts)*56 + hs)*56 + ws2)*256 + dch] = acc[vv] + bpd;
        }
    }
}

extern "C" void kernel_launch(void* const* d_in, const int* in_sizes, int n_in,
                              void* d_out, int out_size, void* d_ws, size_t ws_size,
                              hipStream_t stream) {
    const float* x     = (const float*)d_in[0];
    const float* gamma = (const float*)d_in[1];
    const float* beta  = (const float*)d_in[2];
    const float* wqkv  = (const float*)d_in[3];
    const float* wproj = (const float*)d_in[4];
    const float* bproj = (const float*)d_in[5];
    float* y = (float*)d_out;
    unsigned short* ao = (unsigned short*)d_ws;   // 2048*98*256 bf16 = 103 MB

    dim3 grid(4 * NC_), block(256);
    k_ln_qkv_attn<<<grid, block, 0, stream>>>(x, gamma, beta, wqkv, ao);
    k_proj<<<grid, block, 0, stream>>>(ao, wproj, bproj, y);
}

// Round 2
// 1120.112 us; speedup vs baseline: 6.4609x; 6.4609x over previous
//
#include <hip/hip_runtime.h>
#include <hip/hip_bf16.h>

#define NC_  512
#define VOL_ 98

typedef __attribute__((ext_vector_type(8))) short bf16x8;
typedef __attribute__((ext_vector_type(4))) float f32x4;

#define MFMA(a, b, c) __builtin_amdgcn_mfma_f32_16x16x32_bf16((a), (b), (c), 0, 0, 0)

__device__ __forceinline__ unsigned short f2bf(float f) {
    unsigned u = __float_as_uint(f);
    unsigned r = (u + 0x7fffu + ((u >> 16) & 1u)) >> 16;
    return (unsigned short)r;
}
__device__ __forceinline__ float redmax16(float v) {
    v = fmaxf(v, __shfl_xor(v, 1)); v = fmaxf(v, __shfl_xor(v, 2));
    v = fmaxf(v, __shfl_xor(v, 4)); v = fmaxf(v, __shfl_xor(v, 8));
    return v;
}
__device__ __forceinline__ float redsum16(float v) {
    v += __shfl_xor(v, 1); v += __shfl_xor(v, 2);
    v += __shfl_xor(v, 4); v += __shfl_xor(v, 8);
    return v;
}

// ---------------------------------------------------------------------------
// Kernel 0: convert weights to bf16 (Wq pre-scaled by hd^-0.5)
// ---------------------------------------------------------------------------
__global__ void k_conv(const float* __restrict__ wqkv, const float* __restrict__ wproj,
                       unsigned short* __restrict__ o)
{
    int i = blockIdx.x * 256 + threadIdx.x;
    if (i < 196608) {
        float v = wqkv[i];
        if (i < 65536) v *= 0.17677669529663687f;   // fold q-scale into Wq
        o[i] = f2bf(v);
    } else if (i < 262144) {
        o[i] = f2bf(wproj[i - 196608]);
    }
}

// ---------------------------------------------------------------------------
// Kernel 1: LN + shift + reorder + QKV(MFMA) + flash attention(MFMA) -> ao
// one block per cuboid, 256 threads = 4 waves
// LDS: rn 50176 + Vt 8192 + Qs 8960 + Ks 8960 + Ps 5120 + labs 128 = 81536 B
// ---------------------------------------------------------------------------
__global__ __launch_bounds__(256, 2)
void k_attn(const float* __restrict__ x, const float* __restrict__ gamma,
            const float* __restrict__ beta, const unsigned short* __restrict__ wbf,
            unsigned short* __restrict__ ao)
{
    __shared__ __align__(16) unsigned short rn[VOL_ * 256];   // swizzled [98][256]
    __shared__ __align__(16) unsigned short Vt[32 * 128];     // swizzled [d=32][k=128]
    __shared__ __align__(16) unsigned short Qs[112 * 40];     // [vol][hd] pad 40
    __shared__ __align__(16) unsigned short Ks[112 * 40];     // [vol][hd] pad 40
    __shared__ __align__(16) unsigned short Ps[4][16 * 40];   // per-wave P tile
    __shared__ unsigned char labs[128];

    const int bid = blockIdx.x;
    const int b  = bid >> 9, n = bid & 511;
    const int ti = n >> 6, hi = (n >> 3) & 7, wi = n & 7;
    const int tid = threadIdx.x;
    const int lane = tid & 63, wv = tid >> 6;
    const int c15 = lane & 15, g = lane >> 4, g8 = g * 8, r0 = g * 4;

    // ---- LayerNorm + roll(-1,-3,-3) gather -> swizzled bf16 tile ----
    const float4 gm = *(const float4*)(gamma + lane * 4);
    const float4 be = *(const float4*)(beta  + lane * 4);
    for (int i = wv; i < VOL_; i += 4) {
        int vt = (i >= 49) ? 1 : 0;
        int r  = i - vt * 49;
        int vh = r / 7, vw = r - vh * 7;
        int t = ti * 2 + vt, h = hi * 7 + vh, w = wi * 7 + vw;
        int ts = (t + 1) & 15;
        int hs = h + 3; if (hs >= 56) hs -= 56;
        int ws2 = w + 3; if (ws2 >= 56) ws2 -= 56;
        const float* xp = x + ((((size_t)b * 16 + ts) * 56 + hs) * 56 + ws2) * 256 + lane * 4;
        float4 xv = *(const float4*)xp;
        float s  = xv.x + xv.y + xv.z + xv.w;
        float s2 = xv.x * xv.x + xv.y * xv.y + xv.z * xv.z + xv.w * xv.w;
        #pragma unroll
        for (int o = 1; o < 64; o <<= 1) { s += __shfl_xor(s, o); s2 += __shfl_xor(s2, o); }
        float mu  = s  * (1.0f / 256.0f);
        float var = s2 * (1.0f / 256.0f) - mu * mu;
        float rs  = rsqrtf(var + 1e-5f);
        unsigned a = ((unsigned)(i * 512 + lane * 8)) ^ ((unsigned)((i & 7) << 4));
        uint2 pk;
        pk.x = (unsigned)f2bf((xv.x - mu) * rs * gm.x + be.x)
             | ((unsigned)f2bf((xv.y - mu) * rs * gm.y + be.y) << 16);
        pk.y = (unsigned)f2bf((xv.z - mu) * rs * gm.z + be.z)
             | ((unsigned)f2bf((xv.w - mu) * rs * gm.w + be.w) << 16);
        *(uint2*)((char*)rn + a) = pk;
    }
    if (tid < VOL_) {
        int i = tid;
        int vt = (i >= 49) ? 1 : 0;
        int r  = i - vt * 49;
        int vh = r / 7, vw = r - vh * 7;
        int t = ti * 2 + vt, h = hi * 7 + vh, w = wi * 7 + vw;
        int tr = (t < 14) ? 0 : ((t < 15) ? 1 : 2);
        int hr = (h < 49) ? 0 : ((h < 53) ? 1 : 2);
        int wr = (w < 49) ? 0 : ((w < 53) ? 1 : 2);
        labs[i] = (unsigned char)(tr * 9 + hr * 3 + wr);
    }
    // zero Vt k in [112,128) once (never written by projection)
    for (int z = tid; z < 32 * 16; z += 256) {
        int d = z >> 4, k = 112 + (z & 15);
        unsigned a = (unsigned)((d << 8) + (k << 1)) ^ ((unsigned)((d & 7) << 4));
        *(unsigned short*)((char*)Vt + a) = 0;
    }

    for (int hh = 0; hh < 8; ++hh) {
        __syncthreads();   // prev head attention done; rn/labs ready (hh=0)

        // ---- Q, K, V projections via MFMA: 42 units of (proj, mtile, ctile) ----
        for (int u = wv; u < 42; u += 4) {
            int proj = u / 14, rem = u % 14;
            int mt = rem >> 1, ct = rem & 1;
            const unsigned short* wb = wbf + (size_t)(proj * 256 + hh * 32 + ct * 16 + c15) * 256 + g8;
            bf16x8 B[8];
            #pragma unroll
            for (int kk = 0; kk < 8; ++kk) B[kk] = *(const bf16x8*)(wb + kk * 32);
            f32x4 acc = {0.f, 0.f, 0.f, 0.f};
            int arow = mt * 16 + c15;
            #pragma unroll
            for (int kk = 0; kk < 8; ++kk) {
                unsigned a = (unsigned)(arow * 512 + kk * 64 + g * 16) ^ ((unsigned)((arow & 7) << 4));
                bf16x8 A = *(const bf16x8*)((const char*)rn + a);
                acc = MFMA(A, B[kk], acc);
            }
            int colb = ct * 16 + c15;
            if (proj == 2) {          // V -> Vt (transposed, zero-fill rows >= 98)
                #pragma unroll
                for (int i = 0; i < 4; ++i) {
                    int j = mt * 16 + r0 + i;
                    float v = (j < VOL_) ? acc[i] : 0.f;
                    unsigned a = (unsigned)((colb << 8) + (j << 1)) ^ ((unsigned)((colb & 7) << 4));
                    *(unsigned short*)((char*)Vt + a) = f2bf(v);
                }
            } else {
                unsigned short* dst = (proj == 0) ? Qs : Ks;
                #pragma unroll
                for (int i = 0; i < 4; ++i) {
                    int j = mt * 16 + r0 + i;
                    dst[j * 40 + colb] = f2bf(acc[i]);
                }
            }
        }
        __syncthreads();

        // ---- flash attention per m-tile (wave-private) ----
        for (int mt = wv; mt < 7; mt += 4) {
            bf16x8 qA = *(const bf16x8*)(Qs + (mt * 16 + c15) * 40 + g8);
            int labr[4];
            #pragma unroll
            for (int i = 0; i < 4; ++i) {
                int grow = mt * 16 + r0 + i;
                labr[i] = labs[(grow < VOL_) ? grow : (VOL_ - 1)];
            }
            float m[4]    = {-1e30f, -1e30f, -1e30f, -1e30f};
            float lsum[4] = {0.f, 0.f, 0.f, 0.f};
            f32x4 O0 = {0.f, 0.f, 0.f, 0.f}, O1 = {0.f, 0.f, 0.f, 0.f};
            unsigned short* P = &Ps[wv][0];

            #pragma unroll
            for (int c = 0; c < 4; ++c) {
                f32x4 s0 = {0.f, 0.f, 0.f, 0.f}, s1 = {0.f, 0.f, 0.f, 0.f};
                {
                    bf16x8 kB = *(const bf16x8*)(Ks + (c * 32 + c15) * 40 + g8);
                    s0 = MFMA(qA, kB, s0);
                }
                const bool have1 = (c < 3);
                if (have1) {
                    bf16x8 kB = *(const bf16x8*)(Ks + (c * 32 + 16 + c15) * 40 + g8);
                    s1 = MFMA(qA, kB, s1);
                }
                int col0 = c * 32 + c15, col1 = col0 + 16;
                int lc0 = labs[col0 & 127], lc1 = labs[col1 & 127];
                bool vld0 = (col0 < VOL_), vld1 = have1 && (col1 < VOL_);
                float e0[4], e1[4];
                #pragma unroll
                for (int i = 0; i < 4; ++i) {
                    bool k0 = vld0 && (lc0 == labr[i]);
                    bool k1 = vld1 && (lc1 == labr[i]);
                    float v0 = k0 ? s0[i] : -1e30f;
                    float v1 = k1 ? s1[i] : -1e30f;
                    float cm = redmax16(fmaxf(v0, v1));
                    float mn = fmaxf(m[i], cm);
                    float sc = __expf(m[i] - mn);
                    float x0 = k0 ? __expf(s0[i] - mn) : 0.f;
                    float x1 = k1 ? __expf(s1[i] - mn) : 0.f;
                    float rsum = redsum16(x0 + x1);
                    lsum[i] = lsum[i] * sc + rsum;
                    m[i] = mn;
                    O0[i] *= sc; O1[i] *= sc;
                    e0[i] = x0; e1[i] = x1;
                }
                #pragma unroll
                for (int i = 0; i < 4; ++i) {
                    P[(r0 + i) * 40 + c15]      = f2bf(e0[i]);
                    P[(r0 + i) * 40 + c15 + 16] = f2bf(e1[i]);
                }
                asm volatile("s_waitcnt lgkmcnt(0)" ::: "memory");
                __builtin_amdgcn_sched_barrier(0);
                bf16x8 pA = *(const bf16x8*)(P + c15 * 40 + g8);
                unsigned av0 = (unsigned)((c15 << 8) + ((c * 32 + g8) << 1)) ^ ((unsigned)((c15 & 7) << 4));
                unsigned av1 = (unsigned)(((16 + c15) << 8) + ((c * 32 + g8) << 1)) ^ ((unsigned)((c15 & 7) << 4));
                bf16x8 vB0 = *(const bf16x8*)((const char*)Vt + av0);
                bf16x8 vB1 = *(const bf16x8*)((const char*)Vt + av1);
                O0 = MFMA(pA, vB0, O0);
                O1 = MFMA(pA, vB1, O1);
            }
            #pragma unroll
            for (int i = 0; i < 4; ++i) {
                int grow = mt * 16 + r0 + i;
                if (grow < VOL_) {
                    float inv = 1.0f / lsum[i];
                    size_t base = ((size_t)bid * VOL_ + grow) * 256 + hh * 32;
                    ao[base + c15]      = f2bf(O0[i] * inv);
                    ao[base + 16 + c15] = f2bf(O1[i] * inv);
                }
            }
        }
    }
}

// ---------------------------------------------------------------------------
// Kernel 2: output projection (MFMA) + reverse reorder + roll(+1,+3,+3)
// ---------------------------------------------------------------------------
__global__ __launch_bounds__(256, 2)
void k_proj(const unsigned short* __restrict__ ao, const unsigned short* __restrict__ wpbf,
            const float* __restrict__ bp, float* __restrict__ y)
{
    __shared__ __align__(16) unsigned short tile[112 * 256];   // swizzled
    const int bid = blockIdx.x;
    const int b  = bid >> 9, n = bid & 511;
    const int ti = n >> 6, hi = (n >> 3) & 7, wi = n & 7;
    const int tid = threadIdx.x;
    const int lane = tid & 63, wv = tid >> 6;
    const int c15 = lane & 15, g = lane >> 4, g8 = g * 8, r0 = g * 4;

    const uint4* src = (const uint4*)(ao + (size_t)bid * (VOL_ * 256));
    for (int cidx = tid; cidx < (VOL_ * 256) / 8; cidx += 256) {
        uint4 v = src[cidx];
        int row = cidx >> 5, blk = cidx & 31;
        unsigned a = (unsigned)((row << 9) + (blk << 4)) ^ ((unsigned)((row & 7) << 4));
        *(uint4*)((char*)tile + a) = v;
    }
    __syncthreads();

    for (int u = wv; u < 112; u += 4) {
        int mt = u >> 4, nt = u & 15;
        const unsigned short* wb = wpbf + (size_t)(nt * 16 + c15) * 256 + g8;
        bf16x8 B[8];
        #pragma unroll
        for (int kk = 0; kk < 8; ++kk) B[kk] = *(const bf16x8*)(wb + kk * 32);
        f32x4 acc = {0.f, 0.f, 0.f, 0.f};
        int arow = mt * 16 + c15;
        #pragma unroll
        for (int kk = 0; kk < 8; ++kk) {
            unsigned a = (unsigned)(arow * 512 + kk * 64 + g * 16) ^ ((unsigned)((arow & 7) << 4));
            bf16x8 A = *(const bf16x8*)((const char*)tile + a);
            acc = MFMA(A, B[kk], acc);
        }
        float bias = bp[nt * 16 + c15];
        #pragma unroll
        for (int i = 0; i < 4; ++i) {
            int grow = mt * 16 + r0 + i;
            if (grow < VOL_) {
                int vt = (grow >= 49) ? 1 : 0;
                int r  = grow - vt * 49;
                int vh = r / 7, vw = r - vh * 7;
                int t = ti * 2 + vt, h = hi * 7 + vh, w = wi * 7 + vw;
                int ts = (t + 1) & 15;
                int hs = h + 3; if (hs >= 56) hs -= 56;
                int ws2 = w + 3; if (ws2 >= 56) ws2 -= 56;
                y[((((size_t)b * 16 + ts) * 56 + hs) * 56 + ws2) * 256 + nt * 16 + c15] = acc[i] + bias;
            }
        }
    }
}

extern "C" void kernel_launch(void* const* d_in, const int* in_sizes, int n_in,
                              void* d_out, int out_size, void* d_ws, size_t ws_size,
                              hipStream_t stream) {
    const float* x     = (const float*)d_in[0];
    const float* gamma = (const float*)d_in[1];
    const float* beta  = (const float*)d_in[2];
    const float* wqkv  = (const float*)d_in[3];
    const float* wproj = (const float*)d_in[4];
    const float* bproj = (const float*)d_in[5];
    float* y = (float*)d_out;

    unsigned short* wbf  = (unsigned short*)d_ws;   // 196608 (qkv) + 65536 (proj)
    unsigned short* wpbf = wbf + 196608;
    unsigned short* ao   = wbf + 262144;            // 2048*98*256 bf16 = 102.8 MB

    k_conv<<<dim3(1024), dim3(256), 0, stream>>>(wqkv, wproj, wbf);
    k_attn<<<dim3(4 * NC_), dim3(256), 0, stream>>>(x, gamma, beta, wbf, ao);
    k_proj<<<dim3(4 * NC_), dim3(256), 0, stream>>>(ao, wpbf, bproj, y);
}

// Round 3
// 929.477 us; speedup vs baseline: 7.7860x; 1.2051x over previous
//
#include <hip/hip_runtime.h>
#include <hip/hip_bf16.h>

#define NC_  512
#define VOL_ 98

typedef __attribute__((ext_vector_type(8))) short bf16x8;
typedef __attribute__((ext_vector_type(4))) float f32x4;

#define MFMA(a, b, c) __builtin_amdgcn_mfma_f32_16x16x32_bf16((a), (b), (c), 0, 0, 0)

__device__ __forceinline__ unsigned short f2bf(float f) {
    unsigned u = __float_as_uint(f);
    unsigned r = (u + 0x7fffu + ((u >> 16) & 1u)) >> 16;
    return (unsigned short)r;
}
__device__ __forceinline__ float redmax16(float v) {
    v = fmaxf(v, __shfl_xor(v, 1)); v = fmaxf(v, __shfl_xor(v, 2));
    v = fmaxf(v, __shfl_xor(v, 4)); v = fmaxf(v, __shfl_xor(v, 8));
    return v;
}
__device__ __forceinline__ float redsum16(float v) {
    v += __shfl_xor(v, 1); v += __shfl_xor(v, 2);
    v += __shfl_xor(v, 4); v += __shfl_xor(v, 8);
    return v;
}

// ---------------------------------------------------------------------------
// Kernel 0: convert weights to bf16 (Wq pre-scaled by hd^-0.5)
// ---------------------------------------------------------------------------
__global__ void k_conv(const float* __restrict__ wqkv, const float* __restrict__ wproj,
                       unsigned short* __restrict__ o)
{
    int i = blockIdx.x * 256 + threadIdx.x;
    if (i < 196608) {
        float v = wqkv[i];
        if (i < 65536) v *= 0.17677669529663687f;   // fold q-scale into Wq
        o[i] = f2bf(v);
    } else if (i < 262144) {
        o[i] = f2bf(wproj[i - 196608]);
    }
}

// ---------------------------------------------------------------------------
// Kernel 1: LN + shift + reorder + QKV(MFMA) + two-pass masked softmax attn
// one block per cuboid, 512 threads = 8 waves, 2 blocks/CU (4 waves/SIMD)
// LDS: rn 50176 + Qs 7168 + Ks 7168 + Vt 8192 + Ps 8192 + labs 128 = 81024 B
// ---------------------------------------------------------------------------
__global__ __launch_bounds__(512, 4)
void k_attn(const float* __restrict__ x, const float* __restrict__ gamma,
            const float* __restrict__ beta, const unsigned short* __restrict__ wbf,
            unsigned short* __restrict__ ao)
{
    __shared__ __align__(16) unsigned short rn[VOL_ * 256];   // swz [98][256]
    __shared__ __align__(16) unsigned short Qs[112 * 32];     // swz [112][32]
    __shared__ __align__(16) unsigned short Ks[112 * 32];     // swz [112][32]
    __shared__ __align__(16) unsigned short Vt[32 * 128];     // swz [d=32][k=128]
    __shared__ __align__(16) unsigned short Ps[8][16 * 32];   // per-wave swz [16][32]
    __shared__ unsigned char labs[128];

    const int bid = blockIdx.x;
    const int b  = bid >> 9, n = bid & 511;
    const int ti = n >> 6, hi = (n >> 3) & 7, wi = n & 7;
    const int tid = threadIdx.x;
    const int lane = tid & 63, wv = tid >> 6;
    const int c15 = lane & 15, g = lane >> 4, g8 = g * 8;

    // ---- LayerNorm + roll(-1,-3,-3) gather -> swizzled bf16 tile ----
    const float4 gm = *(const float4*)(gamma + lane * 4);
    const float4 be = *(const float4*)(beta  + lane * 4);
    for (int i = wv; i < VOL_; i += 8) {
        int vt = (i >= 49) ? 1 : 0;
        int r  = i - vt * 49;
        int vh = r / 7, vw = r - vh * 7;
        int t = ti * 2 + vt, h = hi * 7 + vh, w = wi * 7 + vw;
        int ts = (t + 1) & 15;
        int hs = h + 3; if (hs >= 56) hs -= 56;
        int ws2 = w + 3; if (ws2 >= 56) ws2 -= 56;
        const float* xp = x + ((((size_t)b * 16 + ts) * 56 + hs) * 56 + ws2) * 256 + lane * 4;
        float4 xv = *(const float4*)xp;
        float s  = xv.x + xv.y + xv.z + xv.w;
        float s2 = xv.x * xv.x + xv.y * xv.y + xv.z * xv.z + xv.w * xv.w;
        #pragma unroll
        for (int o = 1; o < 64; o <<= 1) { s += __shfl_xor(s, o); s2 += __shfl_xor(s2, o); }
        float mu  = s  * (1.0f / 256.0f);
        float var = s2 * (1.0f / 256.0f) - mu * mu;
        float rs  = rsqrtf(var + 1e-5f);
        unsigned a = ((unsigned)(i * 512 + lane * 8)) ^ ((unsigned)((i & 7) << 4));
        uint2 pk;
        pk.x = (unsigned)f2bf((xv.x - mu) * rs * gm.x + be.x)
             | ((unsigned)f2bf((xv.y - mu) * rs * gm.y + be.y) << 16);
        pk.y = (unsigned)f2bf((xv.z - mu) * rs * gm.z + be.z)
             | ((unsigned)f2bf((xv.w - mu) * rs * gm.w + be.w) << 16);
        *(uint2*)((char*)rn + a) = pk;
    }
    if (tid < VOL_) {
        int i = tid;
        int vt = (i >= 49) ? 1 : 0;
        int r  = i - vt * 49;
        int vh = r / 7, vw = r - vh * 7;
        int t = ti * 2 + vt, h = hi * 7 + vh, w = wi * 7 + vw;
        int tr = (t < 14) ? 0 : ((t < 15) ? 1 : 2);
        int hr = (h < 49) ? 0 : ((h < 53) ? 1 : 2);
        int wr = (w < 49) ? 0 : ((w < 53) ? 1 : 2);
        labs[i] = (unsigned char)(tr * 9 + hr * 3 + wr);
    }
    // zero Vt k in [112,128) once (never written by projection)
    if (tid < 512) {
        int d = tid >> 4, k = 112 + (tid & 15);
        unsigned a = (unsigned)((d << 8) + (k << 1)) ^ ((unsigned)((d & 7) << 4));
        *(unsigned short*)((char*)Vt + a) = 0;
    }

    for (int hh = 0; hh < 8; ++hh) {
        __syncthreads();   // prev head attn done; rn/labs/Vt-pad ready (hh=0)

        // ---- Q, K, V projections via MFMA: 42 units of (proj, mtile, ctile) ----
        for (int u = wv; u < 42; u += 8) {
            int proj = u / 14, rem = u % 14;
            int mt = rem >> 1, ct = rem & 1;
            const unsigned short* wb = wbf + (size_t)(proj * 256 + hh * 32 + ct * 16 + c15) * 256 + g8;
            bf16x8 B[8];
            #pragma unroll
            for (int kk = 0; kk < 8; ++kk) B[kk] = *(const bf16x8*)(wb + kk * 32);
            f32x4 acc = {0.f, 0.f, 0.f, 0.f};
            int arow = mt * 16 + c15;
            #pragma unroll
            for (int kk = 0; kk < 8; ++kk) {
                unsigned a = (unsigned)(arow * 512 + kk * 64 + g * 16) ^ ((unsigned)((arow & 7) << 4));
                bf16x8 A = *(const bf16x8*)((const char*)rn + a);
                acc = MFMA(A, B[kk], acc);
            }
            int colb = ct * 16 + c15;
            if (proj == 2) {          // V -> Vt (transposed, zero-fill rows >= 98)
                #pragma unroll
                for (int i = 0; i < 4; ++i) {
                    int j = mt * 16 + g * 4 + i;
                    float v = (j < VOL_) ? acc[i] : 0.f;
                    unsigned a = (unsigned)((colb << 8) + (j << 1)) ^ ((unsigned)((colb & 7) << 4));
                    *(unsigned short*)((char*)Vt + a) = f2bf(v);
                }
            } else {
                char* dst = (char*)((proj == 0) ? Qs : Ks);
                #pragma unroll
                for (int i = 0; i < 4; ++i) {
                    int j = mt * 16 + g * 4 + i;
                    unsigned a = (unsigned)(j * 64 + colb * 2) ^ ((unsigned)((j & 7) << 4));
                    *(unsigned short*)(dst + a) = f2bf(acc[i]);
                }
            }
        }
        __syncthreads();

        // ---- attention per m-tile: two-pass register softmax ----
        for (int mt = wv; mt < 7; mt += 8) {
            unsigned qa = (unsigned)((mt * 16 + c15) * 64 + g * 16) ^ ((unsigned)((c15 & 7) << 4));
            bf16x8 qA = *(const bf16x8*)((const char*)Qs + qa);
            int labr[4];
            #pragma unroll
            for (int i = 0; i < 4; ++i) {
                int grow = mt * 16 + g * 4 + i;
                labr[i] = labs[(grow < VOL_) ? grow : (VOL_ - 1)];
            }
            // S = Q K^T, 7 independent MFMAs
            f32x4 acc[7];
            #pragma unroll
            for (int c = 0; c < 7; ++c) {
                unsigned ka = (unsigned)((c * 16 + c15) * 64 + g * 16) ^ ((unsigned)((c15 & 7) << 4));
                bf16x8 kB = *(const bf16x8*)((const char*)Ks + ka);
                f32x4 z = {0.f, 0.f, 0.f, 0.f};
                acc[c] = MFMA(qA, kB, z);
            }
            // mask + row max
            bool kok[7];
            #pragma unroll
            for (int c = 0; c < 7; ++c) {
                int col = c * 16 + c15;
                kok[c] = (col < VOL_);
            }
            int labc[7];
            #pragma unroll
            for (int c = 0; c < 7; ++c) labc[c] = labs[(c * 16 + c15) & 127];
            float mx[4];
            #pragma unroll
            for (int i = 0; i < 4; ++i) {
                float m = -1e30f;
                #pragma unroll
                for (int c = 0; c < 7; ++c) {
                    bool ok = kok[c] && (labc[c] == labr[i]);
                    m = fmaxf(m, ok ? acc[c][i] : -1e30f);
                }
                mx[i] = redmax16(m);
            }
            // exp + row sum + pack bf16
            unsigned short pb[7][4];
            float sm[4] = {0.f, 0.f, 0.f, 0.f};
            #pragma unroll
            for (int c = 0; c < 7; ++c) {
                #pragma unroll
                for (int i = 0; i < 4; ++i) {
                    bool ok = kok[c] && (labc[c] == labr[i]);
                    float e = ok ? __expf(acc[c][i] - mx[i]) : 0.f;
                    sm[i] += e;
                    pb[c][i] = f2bf(e);
                }
            }
            #pragma unroll
            for (int i = 0; i < 4; ++i) sm[i] = redsum16(sm[i]);

            // PV: 4 k-frags of 32, P bounced through wave-private swizzled LDS
            f32x4 O0 = {0.f, 0.f, 0.f, 0.f}, O1 = {0.f, 0.f, 0.f, 0.f};
            char* P = (char*)&Ps[wv][0];
            #pragma unroll
            for (int f = 0; f < 4; ++f) {
                #pragma unroll
                for (int i = 0; i < 4; ++i) {
                    int row = g * 4 + i;
                    unsigned sw = (unsigned)((row & 7) << 4);
                    unsigned a0 = (unsigned)(row * 64 + c15 * 2) ^ sw;
                    unsigned a1 = (unsigned)(row * 64 + 32 + c15 * 2) ^ sw;
                    *(unsigned short*)(P + a0) = pb[2 * f][i];
                    *(unsigned short*)(P + a1) = (2 * f + 1 < 7) ? pb[2 * f + 1][i] : (unsigned short)0;
                }
                asm volatile("s_waitcnt lgkmcnt(0)" ::: "memory");
                __builtin_amdgcn_sched_barrier(0);
                unsigned pa = (unsigned)(c15 * 64 + g * 16) ^ ((unsigned)((c15 & 7) << 4));
                bf16x8 pA = *(const bf16x8*)(P + pa);
                unsigned av0 = (unsigned)((c15 << 8) + f * 64 + g * 16) ^ ((unsigned)((c15 & 7) << 4));
                unsigned av1 = (unsigned)(((16 + c15) << 8) + f * 64 + g * 16) ^ ((unsigned)((c15 & 7) << 4));
                bf16x8 vB0 = *(const bf16x8*)((const char*)Vt + av0);
                bf16x8 vB1 = *(const bf16x8*)((const char*)Vt + av1);
                O0 = MFMA(pA, vB0, O0);
                O1 = MFMA(pA, vB1, O1);
            }
            #pragma unroll
            for (int i = 0; i < 4; ++i) {
                int grow = mt * 16 + g * 4 + i;
                if (grow < VOL_) {
                    float inv = 1.0f / sm[i];
                    size_t base = ((size_t)bid * VOL_ + grow) * 256 + hh * 32;
                    ao[base + c15]      = f2bf(O0[i] * inv);
                    ao[base + 16 + c15] = f2bf(O1[i] * inv);
                }
            }
        }
    }
}

// ---------------------------------------------------------------------------
// Kernel 2: output projection (MFMA) + reverse reorder + roll(+1,+3,+3)
// 512 threads = 8 waves, LDS 57344 B -> 2 blocks/CU
// ---------------------------------------------------------------------------
__global__ __launch_bounds__(512, 4)
void k_proj(const unsigned short* __restrict__ ao, const unsigned short* __restrict__ wpbf,
            const float* __restrict__ bp, float* __restrict__ y)
{
    __shared__ __align__(16) unsigned short tile[112 * 256];   // swizzled
    const int bid = blockIdx.x;
    const int b  = bid >> 9, n = bid & 511;
    const int ti = n >> 6, hi = (n >> 3) & 7, wi = n & 7;
    const int tid = threadIdx.x;
    const int lane = tid & 63, wv = tid >> 6;
    const int c15 = lane & 15, g = lane >> 4, g8 = g * 8;

    const uint4* src = (const uint4*)(ao + (size_t)bid * (VOL_ * 256));
    for (int cidx = tid; cidx < (VOL_ * 256) / 8; cidx += 512) {
        uint4 v = src[cidx];
        int row = cidx >> 5, blk = cidx & 31;
        unsigned a = (unsigned)((row << 9) + (blk << 4)) ^ ((unsigned)((row & 7) << 4));
        *(uint4*)((char*)tile + a) = v;
    }
    __syncthreads();

    for (int u = wv; u < 112; u += 8) {
        int mt = u >> 4, nt = u & 15;
        const unsigned short* wb = wpbf + (size_t)(nt * 16 + c15) * 256 + g8;
        bf16x8 B[8];
        #pragma unroll
        for (int kk = 0; kk < 8; ++kk) B[kk] = *(const bf16x8*)(wb + kk * 32);
        f32x4 acc = {0.f, 0.f, 0.f, 0.f};
        int arow = mt * 16 + c15;
        #pragma unroll
        for (int kk = 0; kk < 8; ++kk) {
            unsigned a = (unsigned)(arow * 512 + kk * 64 + g * 16) ^ ((unsigned)((arow & 7) << 4));
            bf16x8 A = *(const bf16x8*)((const char*)tile + a);
            acc = MFMA(A, B[kk], acc);
        }
        float bias = bp[nt * 16 + c15];
        #pragma unroll
        for (int i = 0; i < 4; ++i) {
            int grow = mt * 16 + g * 4 + i;
            if (grow < VOL_) {
                int vt = (grow >= 49) ? 1 : 0;
                int r  = grow - vt * 49;
                int vh = r / 7, vw = r - vh * 7;
                int t = ti * 2 + vt, h = hi * 7 + vh, w = wi * 7 + vw;
                int ts = (t + 1) & 15;
                int hs = h + 3; if (hs >= 56) hs -= 56;
                int ws2 = w + 3; if (ws2 >= 56) ws2 -= 56;
                y[((((size_t)b * 16 + ts) * 56 + hs) * 56 + ws2) * 256 + nt * 16 + c15] = acc[i] + bias;
            }
        }
    }
}

extern "C" void kernel_launch(void* const* d_in, const int* in_sizes, int n_in,
                              void* d_out, int out_size, void* d_ws, size_t ws_size,
                              hipStream_t stream) {
    const float* x     = (const float*)d_in[0];
    const float* gamma = (const float*)d_in[1];
    const float* beta  = (const float*)d_in[2];
    const float* wqkv  = (const float*)d_in[3];
    const float* wproj = (const float*)d_in[4];
    const float* bproj = (const float*)d_in[5];
    float* y = (float*)d_out;

    unsigned short* wbf  = (unsigned short*)d_ws;   // 196608 (qkv) + 65536 (proj)
    unsigned short* wpbf = wbf + 196608;
    unsigned short* ao   = wbf + 262144;            // 2048*98*256 bf16 = 102.8 MB

    k_conv<<<dim3(1024), dim3(256), 0, stream>>>(wqkv, wproj, wbf);
    k_attn<<<dim3(4 * NC_), dim3(512), 0, stream>>>(x, gamma, beta, wbf, ao);
    k_proj<<<dim3(4 * NC_), dim3(512), 0, stream>>>(ao, wpbf, bproj, y);
}

// Round 4
// 625.193 us; speedup vs baseline: 11.5754x; 1.4867x over previous
//
#include <hip/hip_runtime.h>
#include <hip/hip_bf16.h>

#define NC_  512
#define VOL_ 98

typedef __attribute__((ext_vector_type(8))) short bf16x8;
typedef __attribute__((ext_vector_type(4))) float f32x4;
typedef __attribute__((ext_vector_type(16))) float f32x16;
typedef unsigned int u32;
typedef unsigned short u16;

#define MFMA16(a,b,c) __builtin_amdgcn_mfma_f32_16x16x32_bf16((a),(b),(c),0,0,0)
#define MFMA32(a,b,c) __builtin_amdgcn_mfma_f32_32x32x16_bf16((a),(b),(c),0,0,0)

#define SWZ(r)  ((unsigned)((((r) & 7)) << 4))
#define SWZV(d) ((unsigned)(((((d) & 7)) ^ (((d) & 8) >> 1)) << 4))

__device__ __forceinline__ u16 f2bf(float f) {
    u32 u = __float_as_uint(f);
    u32 r = (u + 0x7fffu + ((u >> 16) & 1u)) >> 16;
    return (u16)r;
}
__device__ __forceinline__ u32 cvt_pk(float lo, float hi) {
    u32 r;
    asm("v_cvt_pk_bf16_f32 %0, %1, %2" : "=v"(r) : "v"(lo), "v"(hi));
    return r;
}

// ---------------------------------------------------------------------------
// Kernel 0: convert weights to bf16 (Wq pre-scaled by hd^-0.5)
// ---------------------------------------------------------------------------
__global__ void k_conv(const float* __restrict__ wqkv, const float* __restrict__ wproj,
                       u16* __restrict__ o)
{
    int i = blockIdx.x * 256 + threadIdx.x;
    if (i < 196608) {
        float v = wqkv[i];
        if (i < 65536) v *= 0.17677669529663687f;   // fold q-scale into Wq
        o[i] = f2bf(v);
    } else if (i < 262144) {
        o[i] = f2bf(wproj[i - 196608]);
    }
}

// ---------------------------------------------------------------------------
// Kernel 1: LN + shift + reorder + QKV(32x32 MFMA, reg-B) + S^T attention
// one block per cuboid, 512 threads = 8 waves, 2 blocks/CU
// LDS: rn 50176 + Qs 7168 + Ks 7168 + Vt 8192 + rowbase 448 + labs 128 = 73280
// ---------------------------------------------------------------------------
__global__ __launch_bounds__(512, 4)
void k_attn(const float* __restrict__ x, const float* __restrict__ gamma,
            const float* __restrict__ beta, const u16* __restrict__ wbf,
            u16* __restrict__ ao)
{
    __shared__ __align__(16) u16 rn[VOL_ * 256];   // swz [98][256]
    __shared__ __align__(16) u16 Qs[112 * 32];     // swz [112][32]
    __shared__ __align__(16) u16 Ks[112 * 32];     // swz [112][32]
    __shared__ __align__(16) u16 Vt[32 * 128];     // swz [d=32][k=128]
    __shared__ u32 rowbase[112];
    __shared__ unsigned char labs[128];

    const int bid = blockIdx.x;
    const int b  = bid >> 9, n = bid & 511;
    const int ti = n >> 6, hi = (n >> 3) & 7, wi = n & 7;
    const int tid = threadIdx.x;
    const int lane = tid & 63, wv = tid >> 6;
    const int c15 = lane & 15, g  = lane >> 4;
    const int c31 = lane & 31, g2 = lane >> 5;

    // ---- rowbase (x/y flat offsets incl. roll) + mask labels ----
    if (tid < 128) {
        int i = tid;
        int vt = (i >= 49) ? 1 : 0;
        int r  = i - vt * 49;
        int vh = r / 7, vw = r - vh * 7;
        int t = ti * 2 + vt, h = hi * 7 + vh, w = wi * 7 + vw;
        if (i < 112) {
            int ts = (t + 1) & 15;
            int hs = h + 3; if (hs >= 56) hs -= 56;
            int ws2 = w + 3; if (ws2 >= 56) ws2 -= 56;
            rowbase[i] = (i < VOL_) ? (u32)((((b * 16 + ts) * 56 + hs) * 56 + ws2) * 256) : 0u;
        }
        if (i < VOL_) {
            int tr = (t < 14) ? 0 : ((t < 15) ? 1 : 2);
            int hr = (h < 49) ? 0 : ((h < 53) ? 1 : 2);
            int wr = (w < 49) ? 0 : ((w < 53) ? 1 : 2);
            labs[i] = (unsigned char)(tr * 9 + hr * 3 + wr);
        } else {
            labs[i] = (unsigned char)255;
        }
    }
    // zero Vt k in [112,128) once
    {
        int d = tid >> 4, k = 112 + (tid & 15);
        unsigned a = (unsigned)(d * 256 + k * 2) ^ SWZV(d);
        *(u16*)((char*)Vt + a) = 0;
    }
    __syncthreads();

    // ---- LayerNorm + roll gather -> swizzled bf16 tile ----
    const float4 gm = *(const float4*)(gamma + lane * 4);
    const float4 be = *(const float4*)(beta  + lane * 4);
    for (int i = wv; i < VOL_; i += 8) {
        const float* xp = x + (size_t)rowbase[i] + lane * 4;
        float4 xv = *(const float4*)xp;
        float s  = xv.x + xv.y + xv.z + xv.w;
        float s2 = xv.x * xv.x + xv.y * xv.y + xv.z * xv.z + xv.w * xv.w;
        #pragma unroll
        for (int o = 1; o < 64; o <<= 1) { s += __shfl_xor(s, o); s2 += __shfl_xor(s2, o); }
        float mu  = s  * (1.0f / 256.0f);
        float var = s2 * (1.0f / 256.0f) - mu * mu;
        float rs  = rsqrtf(var + 1e-5f);
        unsigned a = ((unsigned)(i * 512 + lane * 8)) ^ SWZ(i);
        uint2 pk2;
        pk2.x = cvt_pk((xv.x - mu) * rs * gm.x + be.x, (xv.y - mu) * rs * gm.y + be.y);
        pk2.y = cvt_pk((xv.z - mu) * rs * gm.z + be.z, (xv.w - mu) * rs * gm.w + be.w);
        *(uint2*)((char*)rn + a) = pk2;
    }

    // kcol labels per lane (u32 of 4 bytes), constant across heads/mt
    u32 lab4[7];
    #pragma unroll
    for (int c = 0; c < 7; ++c) lab4[c] = *(const u32*)&labs[c * 16 + g * 4];

    for (int hh = 0; hh < 8; ++hh) {
        __syncthreads();   // prev head attn done; rn/labs/Vt-pad ready (hh=0)

        // ---- QKV proj: 12 units of 32x32x16 (3 proj x 4 mtiles), reg-B ----
        for (int u = wv; u < 12; u += 8) {
            int proj = u >> 2, mt = u & 3;
            int arow = mt * 32 + c31; if (arow > 111) arow = 111;
            const u16* wb = wbf + (size_t)(proj * 256 + hh * 32 + c31) * 256 + g2 * 8;
            f32x16 acc = {0,0,0,0,0,0,0,0,0,0,0,0,0,0,0,0};
            #pragma unroll
            for (int half = 0; half < 2; ++half) {
                bf16x8 Bf[8];
                #pragma unroll
                for (int kk = 0; kk < 8; ++kk)
                    Bf[kk] = *(const bf16x8*)(wb + (half * 8 + kk) * 16);
                #pragma unroll
                for (int kk = 0; kk < 8; ++kk) {
                    unsigned a = (unsigned)(arow * 512 + (half * 8 + kk) * 32 + g2 * 16) ^ SWZ(arow);
                    bf16x8 A = *(const bf16x8*)((const char*)rn + a);
                    acc = MFMA32(A, Bf[kk], acc);
                }
            }
            #pragma unroll
            for (int r = 0; r < 16; ++r) {
                int row  = (r & 3) + 8 * (r >> 2) + 4 * g2;
                int grow = mt * 32 + row;
                if (grow < 112) {
                    if (proj == 2) {       // V -> Vt transposed, zero-fill rows >= 98
                        float v = (grow < VOL_) ? acc[r] : 0.f;
                        unsigned a = (unsigned)(c31 * 256 + grow * 2) ^ SWZV(c31);
                        *(u16*)((char*)Vt + a) = f2bf(v);
                    } else {
                        char* dst = (char*)((proj == 0) ? Qs : Ks);
                        unsigned a = (unsigned)(grow * 64 + c31 * 2) ^ SWZ(grow);
                        *(u16*)(dst + a) = f2bf(acc[r]);
                    }
                }
            }
        }
        __syncthreads();

        // ---- attention per m-tile, S^T layout: lane holds S[qrow=c15][kcols] ----
        for (int mt = wv; mt < 7; mt += 8) {
            int qrow = mt * 16 + c15;
            int labr = labs[qrow];
            u32 labr4 = (u32)labr * 0x01010101u;
            unsigned qa = (unsigned)(qrow * 64 + g * 16) ^ SWZ(qrow);
            bf16x8 qB = *(const bf16x8*)((const char*)Qs + qa);

            f32x4 s[7];
            #pragma unroll
            for (int c = 0; c < 7; ++c) {
                int krow = c * 16 + c15;
                unsigned ka = (unsigned)(krow * 64 + g * 16) ^ SWZ(krow);
                bf16x8 kA = *(const bf16x8*)((const char*)Ks + ka);
                f32x4 z = {0.f, 0.f, 0.f, 0.f};
                s[c] = MFMA16(kA, qB, z);
            }
            // pass 1: masked row max (partial in-lane, then across g)
            float mx = -1e30f;
            #pragma unroll
            for (int c = 0; c < 7; ++c) {
                u32 xo = lab4[c] ^ labr4;
                #pragma unroll
                for (int i = 0; i < 4; ++i) {
                    bool ok = ((xo >> (8 * i)) & 255u) == 0u;
                    mx = fmaxf(mx, ok ? s[c][i] : -1e30f);
                }
            }
            mx = fmaxf(mx, __shfl_xor(mx, 16));
            mx = fmaxf(mx, __shfl_xor(mx, 32));
            // pass 2: exp + row sum
            float lsum = 0.f;
            #pragma unroll
            for (int c = 0; c < 7; ++c) {
                u32 xo = lab4[c] ^ labr4;
                #pragma unroll
                for (int i = 0; i < 4; ++i) {
                    bool ok = ((xo >> (8 * i)) & 255u) == 0u;
                    float e = ok ? __expf(s[c][i] - mx) : 0.f;
                    s[c][i] = e;
                    lsum += e;
                }
            }
            lsum += __shfl_xor(lsum, 16);
            lsum += __shfl_xor(lsum, 32);
            float inv = 1.0f / lsum;
            // pass 3: pack normalized P^T to bf16 pairs
            u32 pk[8][2];
            #pragma unroll
            for (int c = 0; c < 7; ++c) {
                pk[c][0] = cvt_pk(s[c][0] * inv, s[c][1] * inv);
                pk[c][1] = cvt_pk(s[c][2] * inv, s[c][3] * inv);
            }
            pk[7][0] = 0u; pk[7][1] = 0u;

            // PV: A-frag built by register shuffle-transpose of P^T
            f32x4 O0 = {0.f, 0.f, 0.f, 0.f}, O1 = {0.f, 0.f, 0.f, 0.f};
            const int src0 = c15 + 32 * (g & 1);
            const bool csel = (g >> 1) != 0;
            #pragma unroll
            for (int f = 0; f < 4; ++f) {
                union { bf16x8 v; u32 w[4]; } pa;
                #pragma unroll
                for (int w = 0; w < 4; ++w) {
                    int src = src0 + 16 * (w >> 1);
                    u32 r0 = (u32)__shfl((int)pk[2 * f][w & 1], src);
                    u32 r1 = (u32)__shfl((int)pk[2 * f + 1][w & 1], src);
                    pa.w[w] = csel ? r1 : r0;
                }
                unsigned av0 = (unsigned)(c15 * 256 + f * 64 + g * 16) ^ SWZV(c15);
                unsigned av1 = (unsigned)((16 + c15) * 256 + f * 64 + g * 16) ^ SWZV(16 + c15);
                bf16x8 vB0 = *(const bf16x8*)((const char*)Vt + av0);
                bf16x8 vB1 = *(const bf16x8*)((const char*)Vt + av1);
                O0 = MFMA16(pa.v, vB0, O0);
                O1 = MFMA16(pa.v, vB1, O1);
            }
            #pragma unroll
            for (int i = 0; i < 4; ++i) {
                int grow = mt * 16 + g * 4 + i;
                if (grow < VOL_) {
                    size_t base = ((size_t)bid * VOL_ + grow) * 256 + hh * 32;
                    ao[base + c15]      = f2bf(O0[i]);
                    ao[base + 16 + c15] = f2bf(O1[i]);
                }
            }
        }
    }
}

// ---------------------------------------------------------------------------
// Kernel 2: output projection (32x32 MFMA, reg-B) + reverse reorder + roll
// 512 threads = 8 waves; 32 units (8 nt x 4 mt)
// ---------------------------------------------------------------------------
__global__ __launch_bounds__(512, 4)
void k_proj(const u16* __restrict__ ao, const u16* __restrict__ wpbf,
            const float* __restrict__ bp, float* __restrict__ y)
{
    __shared__ __align__(16) u16 tile[VOL_ * 256];   // swz [98][256]
    __shared__ u32 rowbase[112];
    const int bid = blockIdx.x;
    const int b  = bid >> 9, n = bid & 511;
    const int ti = n >> 6, hi = (n >> 3) & 7, wi = n & 7;
    const int tid = threadIdx.x;
    const int c31 = (tid & 63) & 31, g2 = (tid & 63) >> 5;
    const int wv = tid >> 6;

    if (tid < 112) {
        int i = tid;
        int vt = (i >= 49) ? 1 : 0;
        int r  = i - vt * 49;
        int vh = r / 7, vw = r - vh * 7;
        int t = ti * 2 + vt, h = hi * 7 + vh, w = wi * 7 + vw;
        int ts = (t + 1) & 15;
        int hs = h + 3; if (hs >= 56) hs -= 56;
        int ws2 = w + 3; if (ws2 >= 56) ws2 -= 56;
        rowbase[i] = (i < VOL_) ? (u32)((((b * 16 + ts) * 56 + hs) * 56 + ws2) * 256) : 0u;
    }
    const uint4* src = (const uint4*)(ao + (size_t)bid * (VOL_ * 256));
    for (int cidx = tid; cidx < (VOL_ * 256) / 8; cidx += 512) {
        uint4 v = src[cidx];
        int row = cidx >> 5, blk = cidx & 31;
        unsigned a = (unsigned)((row << 9) + (blk << 4)) ^ SWZ(row);
        *(uint4*)((char*)tile + a) = v;
    }
    __syncthreads();

    for (int u = wv; u < 32; u += 8) {
        int nt = u >> 2, mt = u & 3;
        int arow = mt * 32 + c31; if (arow > 97) arow = 97;
        const u16* wb = wpbf + (size_t)(nt * 32 + c31) * 256 + g2 * 8;
        f32x16 acc = {0,0,0,0,0,0,0,0,0,0,0,0,0,0,0,0};
        #pragma unroll
        for (int half = 0; half < 2; ++half) {
            bf16x8 Bf[8];
            #pragma unroll
            for (int kk = 0; kk < 8; ++kk)
                Bf[kk] = *(const bf16x8*)(wb + (half * 8 + kk) * 16);
            #pragma unroll
            for (int kk = 0; kk < 8; ++kk) {
                unsigned a = (unsigned)(arow * 512 + (half * 8 + kk) * 32 + g2 * 16) ^ SWZ(arow);
                bf16x8 A = *(const bf16x8*)((const char*)tile + a);
                acc = MFMA32(A, Bf[kk], acc);
            }
        }
        float bias = bp[nt * 32 + c31];
        #pragma unroll
        for (int r = 0; r < 16; ++r) {
            int row = (r & 3) + 8 * (r >> 2) + 4 * g2 + mt * 32;
            if (row < VOL_) {
                y[(size_t)rowbase[row] + nt * 32 + c31] = acc[r] + bias;
            }
        }
    }
}

extern "C" void kernel_launch(void* const* d_in, const int* in_sizes, int n_in,
                              void* d_out, int out_size, void* d_ws, size_t ws_size,
                              hipStream_t stream) {
    const float* x     = (const float*)d_in[0];
    const float* gamma = (const float*)d_in[1];
    const float* beta  = (const float*)d_in[2];
    const float* wqkv  = (const float*)d_in[3];
    const float* wproj = (const float*)d_in[4];
    const float* bproj = (const float*)d_in[5];
    float* y = (float*)d_out;

    u16* wbf  = (u16*)d_ws;            // 196608 (qkv) + 65536 (proj)
    u16* wpbf = wbf + 196608;
    u16* ao   = wbf + 262144;          // 2048*98*256 bf16 = 102.8 MB

    k_conv<<<dim3(1024), dim3(256), 0, stream>>>(wqkv, wproj, wbf);
    k_attn<<<dim3(4 * NC_), dim3(512), 0, stream>>>(x, gamma, beta, wbf, ao);
    k_proj<<<dim3(4 * NC_), dim3(512), 0, stream>>>(ao, wpbf, bproj, y);
}